// Round 12
// baseline (826.160 us; speedup 1.0000x reference)
//
#include <hip/hip_runtime.h>

typedef unsigned short u16;
typedef unsigned int u32;
typedef __attribute__((ext_vector_type(2))) unsigned int u32x2;
typedef __attribute__((ext_vector_type(8))) short bf16x8;
typedef __attribute__((ext_vector_type(4))) float f32x4;

#define CIN 128
#define OC 128
#define NP 1024        // 32*32 spatial
#define KTOT 1152      // 9*128, k = rs*128 + c
#define NSTEP 18
#define BK 64
#define TILE_U16 8192  // 16 KB A-tile per (sample, step)
#define SAMP_U16 (NSTEP * TILE_U16)

typedef const u32 __attribute__((address_space(1)))* gptr_t;
typedef u32 __attribute__((address_space(3)))* lptr_t;

__device__ __forceinline__ u16 f2bf(float f) {
  unsigned b = __builtin_bit_cast(unsigned, f);
  b += 0x7fffu + ((b >> 16) & 1u);   // RNE; inputs are finite
  return (u16)(b >> 16);
}

// w[i][oc][c][r][s] f32 -> wbf2: per (i,step) flat 16KB tile, PRE-SWIZZLED
// (r9-verified): tile[(row*8 + (slotk ^ (row&7)))*8 + e] = w_bf16[k=step*64+slotk*8+e]
__global__ void wcvt_kernel(const float* __restrict__ w, u16* __restrict__ wbf2) {
  __shared__ u16 lds[KTOT];
  const int blk = blockIdx.x;        // i*128 + row(oc)
  const int t = threadIdx.x;         // 0..127
  const int i = blk >> 7, row = blk & 127;
  const float* src = w + (size_t)blk * KTOT;
#pragma unroll
  for (int e = 0; e < 9; ++e) {
    int idx = t + 128 * e;
    lds[idx] = f2bf(src[idx]);
  }
  __syncthreads();
  u16* dst = wbf2 + (size_t)i * SAMP_U16;
  const int rsw = row & 7;
#pragma unroll
  for (int e = 0; e < 9; ++e) {
    const int o = t + 128 * e;       // k = rs*128 + c
    const int s = o >> 6;
    const int slotk = (o >> 3) & 7;
    const int ee = o & 7;
    dst[s * TILE_U16 + (row * 8 + (slotk ^ rsw)) * 8 + ee] = lds[t * 9 + e];
  }
}

// r11 body, phase-ablatable. STAGING: gload_lds A-path + vmcnt ledger.
// DSREAD: LDS->reg fragment loads. XSTAGE: x prologue into Xs. BARRIER:
// the two per-step s_barriers. REPEAT: internal repetitions (unroll 1).
template <bool STAGING, bool DSREAD, bool XSTAGE, bool BARRIER, int REPEAT, bool REAL>
__device__ __forceinline__ void conv_body(const float* __restrict__ x,
                                          const u16* __restrict__ wbf2,
                                          const float* __restrict__ bias,
                                          float* __restrict__ outp) {
  __shared__ u16 Xs[6 * 34 * 128];
  __shared__ u16 Asw[4][TILE_U16];

  const int wg = (int)blockIdx.x;
  const int swz = (wg & 7) * 32 + (wg >> 3);
  const int i  = swz >> 3;
  const int pt = swz & 7;
  const int p0 = pt * 128;
  const int tid = (int)threadIdx.x;  // 512 threads, 8 waves
  const int lane = tid & 63;
  const int wid = tid >> 6;
  const int wm = wid >> 2;
  const int wn = wid & 3;
  const int lcol = lane & 15;
  const int lhi  = lane >> 4;

  const float* xi = x + (size_t)i * CIN * NP;
  const u16*   wt = wbf2 + (size_t)i * SAMP_U16;

#define STG(step) do {                                                 \
    const char* _tb = (const char*)(wt + (step) * TILE_U16);           \
    char* _lb = (char*)&Asw[(step) & 3][0];                            \
    _Pragma("unroll")                                                  \
    for (int _j = 0; _j < 2; ++_j) {                                   \
      const int _off = wid * 2048 + _j * 1024;                         \
      __builtin_amdgcn_global_load_lds(                                \
          (gptr_t)(_tb + _off + lane * 16),                            \
          (lptr_t)(_lb + _off), 16, 0, 0);                             \
    }                                                                  \
  } while (0)

#pragma unroll 1
  for (int rep = 0; rep < REPEAT; ++rep) {
    __syncthreads();                 // WAR guard between repeats

    if constexpr (STAGING) { STG(0); STG(1); }

    if constexpr (XSTAGE) {
      const int xx = tid & 31;
      const int cg = (tid >> 5) & 7;
      const int rh = tid >> 8;
      const int col = xx + 1;
      const int csw = col & 7;
#pragma unroll
      for (int rr = 0; rr < 3; ++rr) {
        const int r = rh * 3 + rr;
        const int yr = 4 * pt - 1 + r;
        float v[16];
        if ((unsigned)yr < 32u) {
          const float* src = xi + (size_t)(cg * 16) * NP + yr * 32 + xx;
#pragma unroll
          for (int j = 0; j < 16; ++j) v[j] = src[(size_t)j * NP];
        } else {
#pragma unroll
          for (int j = 0; j < 16; ++j) v[j] = 0.f;
        }
        u32 pk[8];
#pragma unroll
        for (int m = 0; m < 8; ++m)
          pk[m] = (u32)f2bf(v[2 * m]) | ((u32)f2bf(v[2 * m + 1]) << 16);
#pragma unroll
        for (int q = 0; q < 4; ++q) {
          const int cslot = cg * 2 + (q >> 1);
          const int idx = ((r * 34 + col) * 16 + (cslot ^ csw)) * 8 + (q & 1) * 4;
          *(u32x2*)(&Xs[idx]) = (u32x2){pk[2 * q], pk[2 * q + 1]};
        }
      }
      if (tid < 192) {
        const int r = tid / 32;
        const int hc = ((tid >> 4) & 1) ? 33 : 0;
        const int s = tid & 15;
        const int idx = ((r * 34 + hc) * 16 + (s ^ (hc & 7))) * 8;
        *(bf16x8*)(&Xs[idx]) = (bf16x8){0, 0, 0, 0, 0, 0, 0, 0};
      }
    }

    f32x4 acc[4][2];
#pragma unroll
    for (int mi = 0; mi < 4; ++mi)
#pragma unroll
      for (int ni = 0; ni < 2; ++ni)
        acc[mi][ni] = (f32x4){0.f, 0.f, 0.f, 0.f};

    __syncthreads();

#pragma unroll
    for (int step = 0; step < NSTEP; ++step) {
      const int buf = step & 3;
      const int rs = step >> 1;
      const int r3 = rs / 3;
      const int dy = r3 - 1;
      const int dx = (rs - r3 * 3) - 1;
      const int c0s = (step & 1) * 8;

      if constexpr (STAGING) {
        if (step + 2 < NSTEP) STG(step + 2);
        if (step + 2 < NSTEP) {
          asm volatile("s_waitcnt vmcnt(4)" ::: "memory");
        } else if (step + 1 < NSTEP) {
          asm volatile("s_waitcnt vmcnt(2)" ::: "memory");
        } else {
          asm volatile("s_waitcnt vmcnt(0)" ::: "memory");
        }
      }
      if constexpr (BARRIER) __builtin_amdgcn_s_barrier();
      __builtin_amdgcn_sched_barrier(0);

      bf16x8 af[2][4], bfr[2][2];
      if constexpr (DSREAD) {
#pragma unroll
        for (int kkk = 0; kkk < 2; ++kkk) {
#pragma unroll
          for (int mi = 0; mi < 4; ++mi) {
            const int row = wm * 64 + mi * 16 + lcol;
            const int slot = (kkk * 4 + lhi) ^ (row & 7);
            af[kkk][mi] = *(const bf16x8*)(&Asw[buf][row * BK + slot * 8]);
          }
#pragma unroll
          for (int ni = 0; ni < 2; ++ni) {
            const int srow = wn + 1 + dy;
            const int col  = ni * 16 + lcol + 1 + dx;
            const int cslot = c0s + kkk * 4 + lhi;
            const int idx = ((srow * 34 + col) * 16 + (cslot ^ (col & 7))) * 8;
            bfr[kkk][ni] = *(const bf16x8*)(&Xs[idx]);
          }
        }
      } else {
#pragma unroll
        for (int kkk = 0; kkk < 2; ++kkk) {
#pragma unroll
          for (int mi = 0; mi < 4; ++mi)
#pragma unroll
            for (int e = 0; e < 8; ++e) af[kkk][mi][e] = (short)(lane + e + kkk);
#pragma unroll
          for (int ni = 0; ni < 2; ++ni)
#pragma unroll
            for (int e = 0; e < 8; ++e) bfr[kkk][ni][e] = (short)(lane - e + ni);
        }
      }

      __builtin_amdgcn_s_setprio(1);
#pragma unroll
      for (int kkk = 0; kkk < 2; ++kkk)
#pragma unroll
        for (int mi = 0; mi < 4; ++mi)
#pragma unroll
          for (int ni = 0; ni < 2; ++ni)
            acc[mi][ni] = __builtin_amdgcn_mfma_f32_16x16x32_bf16(
                af[kkk][mi], bfr[kkk][ni], acc[mi][ni], 0, 0, 0);
      __builtin_amdgcn_s_setprio(0);
      if constexpr (BARRIER) __builtin_amdgcn_s_barrier();
    }

    // epilogue: scratch (diag) or real output (+bias)
    const int row0 = lhi * 4;
#pragma unroll
    for (int mi = 0; mi < 4; ++mi) {
      const int oc = wm * 64 + mi * 16 + row0;
#pragma unroll
      for (int jj = 0; jj < 4; ++jj) {
        float bv = 0.f;
        if constexpr (REAL) bv = bias[i * OC + oc + jj];
        float* orow = outp + ((size_t)i * OC + oc + jj) * NP;
#pragma unroll
        for (int ni = 0; ni < 2; ++ni) {
          const int pg = p0 + wn * 32 + ni * 16 + lcol;
          orow[pg] = acc[mi][ni][jj] + bv;
        }
      }
    }
  }
#undef STG
}

__global__ __launch_bounds__(512, 1) void conv_v0_full(
    const float* __restrict__ x, const u16* __restrict__ w2,
    const float* __restrict__ b, float* __restrict__ o) {
  conv_body<true, true, true, true, 8, false>(x, w2, b, o);
}
__global__ __launch_bounds__(512, 1) void conv_v1_nostage(
    const float* __restrict__ x, const u16* __restrict__ w2,
    const float* __restrict__ b, float* __restrict__ o) {
  conv_body<false, true, true, true, 8, false>(x, w2, b, o);
}
__global__ __launch_bounds__(512, 1) void conv_v2_nods(
    const float* __restrict__ x, const u16* __restrict__ w2,
    const float* __restrict__ b, float* __restrict__ o) {
  conv_body<true, false, true, true, 10, false>(x, w2, b, o);
}
__global__ __launch_bounds__(512, 1) void conv_v3_noxstage(
    const float* __restrict__ x, const u16* __restrict__ w2,
    const float* __restrict__ b, float* __restrict__ o) {
  conv_body<true, true, false, true, 8, false>(x, w2, b, o);
}
__global__ __launch_bounds__(512, 1) void conv_v4_nobar(
    const float* __restrict__ x, const u16* __restrict__ w2,
    const float* __restrict__ b, float* __restrict__ o) {
  conv_body<true, true, true, false, 8, false>(x, w2, b, o);
}
__global__ __launch_bounds__(512, 1) void conv_real(
    const float* __restrict__ x, const u16* __restrict__ w2,
    const float* __restrict__ b, float* __restrict__ o) {
  conv_body<true, true, true, true, 1, true>(x, w2, b, o);
}

extern "C" void kernel_launch(void* const* d_in, const int* in_sizes, int n_in,
                              void* d_out, int out_size, void* d_ws, size_t ws_size,
                              hipStream_t stream) {
  const float* x    = (const float*)d_in[0];
  const float* w    = (const float*)d_in[1];
  const float* bias = (const float*)d_in[2];
  float* out = (float*)d_out;
  u16* wbf2 = (u16*)d_ws;                              // 9.44 MB
  float* scr = (float*)((char*)d_ws + (64u << 20));    // 16.8 MB scratch

  wcvt_kernel<<<dim3(32 * OC), dim3(128), 0, stream>>>(w, wbf2);
  // diagnostic ablation matrix (write scratch; visible as rocprof rows)
  conv_v0_full   <<<dim3(256), dim3(512), 0, stream>>>(x, wbf2, bias, scr);
  conv_v1_nostage<<<dim3(256), dim3(512), 0, stream>>>(x, wbf2, bias, scr);
  conv_v2_nods   <<<dim3(256), dim3(512), 0, stream>>>(x, wbf2, bias, scr);
  conv_v3_noxstage<<<dim3(256), dim3(512), 0, stream>>>(x, wbf2, bias, scr);
  conv_v4_nobar  <<<dim3(256), dim3(512), 0, stream>>>(x, wbf2, bias, scr);
  // the real thing (validated output)
  conv_real      <<<dim3(256), dim3(512), 0, stream>>>(x, wbf2, bias, out);
}

// Round 14
// 39.646 us; speedup vs baseline: 20.8382x; 20.8382x over previous
//
#include <hip/hip_runtime.h>

typedef unsigned short u16;
typedef unsigned int u32;
typedef __attribute__((ext_vector_type(4))) unsigned int u32x4;
typedef __attribute__((ext_vector_type(8))) short bf16x8;
typedef __attribute__((ext_vector_type(4))) float f32x4;

#define CIN 128
#define OC 128
#define NP 1024        // 32*32 spatial
#define KTOT 1152      // 9*128, k = rs*128 + c
#define NSTEP 18
#define BK 64
#define TILE_U16 8192  // 16 KB A-tile per (sample, step)
#define SAMP_U16 (NSTEP * TILE_U16)
// xbf: [32 samples][34 rows][36 cols][128 ch] bf16, pre-swizzled 16B slots
#define XROW_U16 (36 * 128)              // 4608 u16 = 9216 B per row
#define XSAMP_U16 (34 * XROW_U16)
#define XBF_BYTES ((size_t)32 * XSAMP_U16 * 2)   // 10,027,008 B

typedef const u32 __attribute__((address_space(1)))* gptr_t;
typedef u32 __attribute__((address_space(3)))* lptr_t;

__device__ __forceinline__ u16 f2bf(float f) {
  unsigned b = __builtin_bit_cast(unsigned, f);
  b += 0x7fffu + ((b >> 16) & 1u);   // RNE; inputs are finite
  return (u16)(b >> 16);
}

// ---- prep: wcvt (blocks 0..4095, r9-proven) + xcvt (blocks 4096..5119) ----
// wcvt: w[i][oc][c][r][s] f32 -> wbf2 per (i,step) flat 16KB PRE-SWIZZLED tile:
//   tile[(row*8 + (slotk^(row&7)))*8 + e] = w_bf16[k=step*64+slotk*8+e]
// xcvt: x[i][c][y][xx] f32 -> xbf[i][y+1][xx+1][c] bf16, slot' = cslot^(col&7)
//   column pitch = 128 u16 (16 slots x 8 u16).  [r13 bug: was col*256 -> fixed]
__global__ void prep_kernel(const float* __restrict__ w,
                            const float* __restrict__ x,
                            u16* __restrict__ wbf2,
                            u16* __restrict__ xbf) {
  const int blk = blockIdx.x;
  const int t = threadIdx.x;         // 0..127
  if (blk < 4096) {                  // ---------------- wcvt ----------------
    __shared__ u16 lds[KTOT];
    const int i = blk >> 7, row = blk & 127;
    const float* src = w + (size_t)blk * KTOT;
#pragma unroll
    for (int e = 0; e < 9; ++e) {
      int idx = t + 128 * e;
      lds[idx] = f2bf(src[idx]);
    }
    __syncthreads();
    u16* dst = wbf2 + (size_t)i * SAMP_U16;
    const int rsw = row & 7;
#pragma unroll
    for (int e = 0; e < 9; ++e) {
      const int o = t + 128 * e;     // k = rs*128 + c
      const int s = o >> 6;
      const int slotk = (o >> 3) & 7;
      const int ee = o & 7;
      dst[s * TILE_U16 + (row * 8 + (slotk ^ rsw)) * 8 + ee] = lds[t * 9 + e];
    }
  } else {                           // ---------------- xcvt ----------------
    const int b = blk - 4096;        // i*32 + y
    const int i = b >> 5, y = b & 31;
    const int xx = t & 31;           // image col
    const int cg2 = t >> 5;          // 0..3, 32 channels each
    const float* src = x + ((size_t)(i * CIN + cg2 * 32) * 32 + y) * 32 + xx;
    float v[32];
#pragma unroll
    for (int j = 0; j < 32; ++j) v[j] = src[(size_t)j * NP];
    u32 pk[16];
#pragma unroll
    for (int m = 0; m < 16; ++m)
      pk[m] = (u32)f2bf(v[2 * m]) | ((u32)f2bf(v[2 * m + 1]) << 16);
    const int col = xx + 1;
    u16* rowp = xbf + (size_t)(i * 34 + (y + 1)) * XROW_U16 + col * 128;
#pragma unroll
    for (int h = 0; h < 4; ++h) {    // slot = cg2*4 + h covers ch cg2*32+h*8..+7
      const int sl = (cg2 * 4 + h) ^ (col & 7);
      *(u32x4*)(rowp + sl * 8) =
          (u32x4){pk[h * 4], pk[h * 4 + 1], pk[h * 4 + 2], pk[h * 4 + 3]};
    }
  }
}

// conv: 64-px tiles (2 image rows), 256 thr / 4 waves, wave tile 64oc x 32px.
// Xs (4 rows x 36 cols x 128ch, pre-swizzled) DMA-filled from xbf; A double-
// buffered 16KB tiles DMA-filled from wbf2. LDS = 36,864 + 32,768 = 69,632 B
// -> 2 blocks/CU, 8 waves. One barrier per K-step; STAGE issued after the
// barrier (cross-wave WAR-safe with 2 buffers); vmcnt(0) drains a 4-deep,
// ~1-phase-old queue (near-zero stall).
__global__ __launch_bounds__(256, 2) void conv_mfma(
    const u16* __restrict__ xbf,
    const u16* __restrict__ wbf2,
    const float* __restrict__ bias,  // [32][1][128]
    float* __restrict__ out) {       // [32][1][128][32][32]
  __shared__ u16 Xs[4 * 36 * 128];   // 36,864 B
  __shared__ u16 Asw[2][TILE_U16];   // 32,768 B

  // grid 512 = 8 XCDs x 64; bijective XCD swizzle
  const int wg = (int)blockIdx.x;
  const int swz = (wg & 7) * 64 + (wg >> 3);
  const int i  = swz >> 4;           // sample
  const int pt = swz & 15;           // 64-px tile = image rows {2pt, 2pt+1}
  const int p0 = pt * 64;
  const int tid = (int)threadIdx.x;
  const int lane = tid & 63;
  const int wid = tid >> 6;
  const int wm = wid >> 1;           // oc half
  const int wn = wid & 1;            // image row within tile
  const int lcol = lane & 15;
  const int lhi  = lane >> 4;

  const u16* wt = wbf2 + (size_t)i * SAMP_U16;
  const u16* xsrc = xbf + (size_t)(i * 34 + 2 * pt) * XROW_U16;  // 4 rows

#define STAGE(step) do {                                               \
    const char* _tb = (const char*)(wt + (step) * TILE_U16);           \
    char* _lb = (char*)&Asw[(step) & 1][0];                            \
    _Pragma("unroll")                                                  \
    for (int _r = 0; _r < 4; ++_r) {                                   \
      const int _off = _r * 4096 + tid * 16;                           \
      __builtin_amdgcn_global_load_lds(                                \
          (gptr_t)(_tb + _off), (lptr_t)(_lb + _off), 16, 0, 0);       \
    }                                                                  \
  } while (0)

  // prologue: Xs DMA (9) then A0 (4) then A1 (4); vmcnt(4) -> Xs+A0 done
  {
    const char* _xs = (const char*)xsrc;
    char* _xl = (char*)&Xs[0];
#pragma unroll
    for (int r = 0; r < 9; ++r) {
      const int off = r * 4096 + tid * 16;
      __builtin_amdgcn_global_load_lds((gptr_t)(_xs + off),
                                       (lptr_t)(_xl + off), 16, 0, 0);
    }
  }
  STAGE(0);
  STAGE(1);

  f32x4 acc[4][2];
#pragma unroll
  for (int mi = 0; mi < 4; ++mi)
#pragma unroll
    for (int ni = 0; ni < 2; ++ni)
      acc[mi][ni] = (f32x4){0.f, 0.f, 0.f, 0.f};

  asm volatile("s_waitcnt vmcnt(4)" ::: "memory");
  __builtin_amdgcn_s_barrier();
  __builtin_amdgcn_sched_barrier(0);

#pragma unroll
  for (int step = 0; step < NSTEP; ++step) {
    const int buf = step & 1;
    const int rs = step >> 1;
    const int r3 = rs / 3;
    const int dy = r3 - 1;
    const int dx = (rs - r3 * 3) - 1;
    const int c0s = (step & 1) * 8;

    // ---- 12 ds_read + 16 MFMA ----
    bf16x8 af[2][4], bfr[2][2];
#pragma unroll
    for (int kkk = 0; kkk < 2; ++kkk) {
#pragma unroll
      for (int mi = 0; mi < 4; ++mi) {
        const int row = wm * 64 + mi * 16 + lcol;
        const int slot = (kkk * 4 + lhi) ^ (row & 7);
        af[kkk][mi] = *(const bf16x8*)(&Asw[buf][row * BK + slot * 8]);
      }
#pragma unroll
      for (int ni = 0; ni < 2; ++ni) {
        const int srow = wn + 1 + dy;                 // 0..3
        const int col  = ni * 16 + lcol + 1 + dx;     // 0..34 (<36)
        const int cslot = c0s + kkk * 4 + lhi;
        const int idx = ((srow * 36 + col) * 16 + (cslot ^ (col & 7))) * 8;
        bfr[kkk][ni] = *(const bf16x8*)(&Xs[idx]);
      }
    }
    __builtin_amdgcn_s_setprio(1);
#pragma unroll
    for (int kkk = 0; kkk < 2; ++kkk)
#pragma unroll
      for (int mi = 0; mi < 4; ++mi)
#pragma unroll
        for (int ni = 0; ni < 2; ++ni)
          acc[mi][ni] = __builtin_amdgcn_mfma_f32_16x16x32_bf16(
              af[kkk][mi], bfr[kkk][ni], acc[mi][ni], 0, 0, 0);
    __builtin_amdgcn_s_setprio(0);

    // end of step: A(step+1) resident (queue is only its 4 instrs, issued a
    // full phase ago); barrier; then stage step+2 into the buffer this step
    // just finished reading (all waves past barrier -> WAR-safe).
    if (step + 1 < NSTEP) {
      asm volatile("s_waitcnt vmcnt(0)" ::: "memory");
      __builtin_amdgcn_s_barrier();
      __builtin_amdgcn_sched_barrier(0);
      if (step + 2 < NSTEP) STAGE(step + 2);
    }
  }

  // ---- epilogue (proven): C/D col=lane&15, row=(lane>>4)*4+j ----
  const int row0 = lhi * 4;
#pragma unroll
  for (int mi = 0; mi < 4; ++mi) {
    const int oc = wm * 64 + mi * 16 + row0;
#pragma unroll
    for (int jj = 0; jj < 4; ++jj) {
      const float bv = bias[i * OC + oc + jj];
      float* orow = out + ((size_t)i * OC + oc + jj) * NP;
#pragma unroll
      for (int ni = 0; ni < 2; ++ni) {
        const int pg = p0 + wn * 32 + ni * 16 + lcol;
        orow[pg] = acc[mi][ni][jj] + bv;
      }
    }
  }
#undef STAGE
}

extern "C" void kernel_launch(void* const* d_in, const int* in_sizes, int n_in,
                              void* d_out, int out_size, void* d_ws, size_t ws_size,
                              hipStream_t stream) {
  const float* x    = (const float*)d_in[0];
  const float* w    = (const float*)d_in[1];
  const float* bias = (const float*)d_in[2];
  float* out = (float*)d_out;
  u16* wbf2 = (u16*)d_ws;                                // 9.44 MB
  u16* xbf  = (u16*)((char*)d_ws + (16u << 20));         // 10.03 MB

  hipMemsetAsync(xbf, 0, XBF_BYTES, stream);             // zero halos
  prep_kernel<<<dim3(5120), dim3(128), 0, stream>>>(w, x, wbf2, xbf);
  conv_mfma<<<dim3(512), dim3(256), 0, stream>>>(xbf, wbf2, bias, out);
}

// Round 15
// 30.712 us; speedup vs baseline: 26.9006x; 1.2909x over previous
//
#include <hip/hip_runtime.h>

typedef unsigned short u16;
typedef unsigned int u32;
typedef __attribute__((ext_vector_type(4))) unsigned int u32x4;
typedef __attribute__((ext_vector_type(8))) short bf16x8;
typedef __attribute__((ext_vector_type(4))) float f32x4;

#define CIN 128
#define OC 128
#define NP 1024        // 32*32 spatial
#define KTOT 1152      // 9*128, k = rs*128 + c
#define NSTEP 18
#define BK 64
#define TILE_U16 8192  // 16 KB A-tile per (sample, step)
#define SAMP_U16 (NSTEP * TILE_U16)
// xbf: [32][34 rows][36 cols][128 ch] bf16, pre-swizzled 16B slots
#define XROW_U16 (36 * 128)              // 4608 u16 = 9216 B per row
#define XSAMP_U16 (34 * XROW_U16)

typedef const u32 __attribute__((address_space(1)))* gptr_t;
typedef u32 __attribute__((address_space(3)))* lptr_t;

__device__ __forceinline__ u16 f2bf(float f) {
  unsigned b = __builtin_bit_cast(unsigned, f);
  b += 0x7fffu + ((b >> 16) & 1u);   // RNE; inputs are finite
  return (u16)(b >> 16);
}

// prep: blocks [0,4096) wcvt (r9-proven) | [4096,5120) xcvt | [5120,5184) halo rows
__global__ void prep_kernel(const float* __restrict__ w,
                            const float* __restrict__ x,
                            u16* __restrict__ wbf2,
                            u16* __restrict__ xbf) {
  const int blk = blockIdx.x;
  const int t = threadIdx.x;         // 0..127
  if (blk < 4096) {                  // ---------------- wcvt ----------------
    __shared__ u16 lds[KTOT];
    const int i = blk >> 7, row = blk & 127;
    const float* src = w + (size_t)blk * KTOT;
#pragma unroll
    for (int e = 0; e < 9; ++e) {
      int idx = t + 128 * e;
      lds[idx] = f2bf(src[idx]);
    }
    __syncthreads();
    u16* dst = wbf2 + (size_t)i * SAMP_U16;
    const int rsw = row & 7;
#pragma unroll
    for (int e = 0; e < 9; ++e) {
      const int o = t + 128 * e;     // k = rs*128 + c
      const int s = o >> 6;
      const int slotk = (o >> 3) & 7;
      const int ee = o & 7;
      dst[s * TILE_U16 + (row * 8 + (slotk ^ rsw)) * 8 + ee] = lds[t * 9 + e];
    }
  } else if (blk < 5120) {           // ---------------- xcvt ----------------
    __shared__ u16 rowbuf[XROW_U16]; // one full pre-swizzled 36-col row (9216 B)
    const int b = blk - 4096;        // i*32 + y
    const int i = b >> 5, y = b & 31;
    const int xx = t & 31;           // image col
    const int cg2 = t >> 5;          // 0..3, 32 channels each
    const float* src = x + ((size_t)(i * CIN + cg2 * 32) * 32 + y) * 32 + xx;
    float v[32];
#pragma unroll
    for (int j = 0; j < 32; ++j) v[j] = src[(size_t)j * NP];
    u32 pk[16];
#pragma unroll
    for (int m = 0; m < 16; ++m)
      pk[m] = (u32)f2bf(v[2 * m]) | ((u32)f2bf(v[2 * m + 1]) << 16);
    const int col = xx + 1;
#pragma unroll
    for (int h = 0; h < 4; ++h) {    // slot cg2*4+h covers ch cg2*32+h*8..+7
      const int sl = (cg2 * 4 + h) ^ (col & 7);
      *(u32x4*)(&rowbuf[col * 128 + sl * 8]) =
          (u32x4){pk[h * 4], pk[h * 4 + 1], pk[h * 4 + 2], pk[h * 4 + 3]};
    }
    // halo cols {0,33,34,35}: 4 cols x 256B = 64 x 16B chunks
    if (t < 64) {
      const int hcs[4] = {0, 33, 34, 35};
      const int hc = hcs[t >> 4];
      *(u32x4*)(&rowbuf[hc * 128 + (t & 15) * 8]) = (u32x4){0, 0, 0, 0};
    }
    __syncthreads();
    // linear coalesced write of the full 9216 B row
    u16* dst = xbf + (size_t)(i * 34 + (y + 1)) * XROW_U16;
#pragma unroll
    for (int j = 0; j < 4; ++j)
      *(u32x4*)(&dst[j * 1024 + t * 8]) = *(const u32x4*)(&rowbuf[j * 1024 + t * 8]);
    if (t < 64)
      *(u32x4*)(&dst[4096 + t * 8]) = *(const u32x4*)(&rowbuf[4096 + t * 8]);
  } else {                           // ---------------- halo rows 0 / 33 ----
    const int b2 = blk - 5120;       // i*2 + (top/bottom)
    const int i = b2 >> 1;
    const int r = (b2 & 1) ? 33 : 0;
    u16* dst = xbf + (size_t)(i * 34 + r) * XROW_U16;
#pragma unroll
    for (int j = 0; j < 4; ++j)
      *(u32x4*)(&dst[j * 1024 + t * 8]) = (u32x4){0, 0, 0, 0};
    if (t < 64) *(u32x4*)(&dst[4096 + t * 8]) = (u32x4){0, 0, 0, 0};
  }
}

// conv: 128oc x 128px tiles (4 image rows), 256 thr / 4 waves, wave 64oc x 64px
// (m4n4, reads/MFMA = 0.5). Xs = 6 full xbf rows (55.3 KB) DMA'd linearly;
// A single-buffered 16 KB with register prefetch (r8-proven macros).
// LDS = 55,296 + 16,384 = 71,680 B -> 2 blocks/CU, 8 waves/CU.
__global__ __launch_bounds__(256, 2) void conv_mfma(
    const u16* __restrict__ xbf,
    const u16* __restrict__ wbf2,
    const float* __restrict__ bias,  // [32][1][128]
    float* __restrict__ out) {       // [32][1][128][32][32]
  __shared__ u16 Xs[6 * XROW_U16];   // 55,296 B
  __shared__ u16 Asw[TILE_U16];      // 16,384 B

  // grid 256 = 8 XCDs x 32; bijective XCD swizzle -> 4 samples per XCD
  const int wg = (int)blockIdx.x;
  const int swz = (wg & 7) * 32 + (wg >> 3);
  const int i  = swz >> 3;           // sample 0..31
  const int pt = swz & 7;            // 128-px tile = image rows 4pt..4pt+3
  const int p0 = pt * 128;
  const int tid = (int)threadIdx.x;
  const int lane = tid & 63;
  const int wid = tid >> 6;
  const int wm = wid >> 1;           // oc half
  const int wn = wid & 1;            // px half (2 image rows)
  const int lcol = lane & 15;
  const int lhi  = lane >> 4;

  const u16* wt = wbf2 + (size_t)i * SAMP_U16;
  const u16* abase = wt + tid * 8;   // reg-prefetch base (linear tile copy)

  bf16x8 ar[4];
#define LOADA(step) do {                                          \
    const u16* _a = abase + (step) * TILE_U16;                    \
    _Pragma("unroll")                                             \
    for (int e = 0; e < 4; ++e)                                   \
      ar[e] = *(const bf16x8*)(_a + e * 2048);                    \
  } while (0)
#define STOREA() do {                                             \
    _Pragma("unroll")                                             \
    for (int e = 0; e < 4; ++e)                                   \
      *(bf16x8*)(&Asw[tid * 8 + e * 2048]) = ar[e];               \
  } while (0)

  LOADA(0);                          // A0 -> regs, in flight during Xs DMA

  // Xs DMA: 6 rows x 9216 B, linear; per row 2x16B + 1x4B uniform instrs
  {
    const char* gsrc = (const char*)(xbf + (size_t)(i * 34 + 4 * pt) * XROW_U16);
    char* ldst = (char*)&Xs[0];
#pragma unroll
    for (int r = 0; r < 6; ++r) {
      const int rb = r * 9216;
#pragma unroll
      for (int q = 0; q < 2; ++q) {
        const int off = rb + q * 4096 + tid * 16;
        __builtin_amdgcn_global_load_lds((gptr_t)(gsrc + off),
                                         (lptr_t)(ldst + off), 16, 0, 0);
      }
      const int off4 = rb + 8192 + tid * 4;
      __builtin_amdgcn_global_load_lds((gptr_t)(gsrc + off4),
                                       (lptr_t)(ldst + off4), 4, 0, 0);
    }
  }

  f32x4 acc[4][4];
#pragma unroll
  for (int mi = 0; mi < 4; ++mi)
#pragma unroll
    for (int ni = 0; ni < 4; ++ni)
      acc[mi][ni] = (f32x4){0.f, 0.f, 0.f, 0.f};

  asm volatile("s_waitcnt vmcnt(0)" ::: "memory");  // Xs + A0 regs resident
  STOREA();
  __syncthreads();                   // Xs + Asw(0) visible

#pragma unroll
  for (int step = 0; step < NSTEP; ++step) {
    const int rs = step >> 1;
    const int r3 = rs / 3;
    const int dy = r3 - 1;
    const int dx = (rs - r3 * 3) - 1;
    const int c0s = (step & 1) * 8;  // channel-slot base (64ch/8)

    // prefetch next A-tile into registers (16 VGPR; survives barriers)
    if (step + 1 < NSTEP) LOADA(step + 1);

    // ---- 16 ds_read + 32 MFMA per wave ----
#pragma unroll
    for (int kkk = 0; kkk < 2; ++kkk) {
      bf16x8 af[4], bfr[4];
#pragma unroll
      for (int mi = 0; mi < 4; ++mi) {
        const int row = wm * 64 + mi * 16 + lcol;
        const int slot = (kkk * 4 + lhi) ^ (row & 7);
        af[mi] = *(const bf16x8*)(&Asw[row * BK + slot * 8]);
      }
#pragma unroll
      for (int ni = 0; ni < 4; ++ni) {
        const int srow = wn * 2 + (ni >> 1) + 1 + dy;   // 0..5
        const int col  = (ni & 1) * 16 + lcol + 1 + dx; // 0..33
        const int cslot = c0s + kkk * 4 + lhi;
        const int idx = ((srow * 36 + col) * 16 + (cslot ^ (col & 7))) * 8;
        bfr[ni] = *(const bf16x8*)(&Xs[idx]);
      }
      __builtin_amdgcn_s_setprio(1);
#pragma unroll
      for (int mi = 0; mi < 4; ++mi)
#pragma unroll
        for (int ni = 0; ni < 4; ++ni)
          acc[mi][ni] = __builtin_amdgcn_mfma_f32_16x16x32_bf16(
              af[mi], bfr[ni], acc[mi][ni], 0, 0, 0);
      __builtin_amdgcn_s_setprio(0);
    }

    // single-buffer A: readers done -> overwrite -> visible
    if (step + 1 < NSTEP) {
      __syncthreads();
      STOREA();                      // compiler waits ar's vmcnt here
      __syncthreads();
    }
  }

  // ---- epilogue (r8-proven m4n4): C/D col=lane&15, row=lhi*4+j ----
  const int row0 = lhi * 4;
#pragma unroll
  for (int mi = 0; mi < 4; ++mi) {
    const int oc = wm * 64 + mi * 16 + row0;
#pragma unroll
    for (int jj = 0; jj < 4; ++jj) {
      const float bv = bias[i * OC + oc + jj];
      float* orow = out + ((size_t)i * OC + oc + jj) * NP;
#pragma unroll
      for (int ni = 0; ni < 4; ++ni) {
        const int pg = p0 + wn * 64 + ni * 16 + lcol;
        orow[pg] = acc[mi][ni][jj] + bv;
      }
    }
  }
#undef LOADA
#undef STOREA
}

extern "C" void kernel_launch(void* const* d_in, const int* in_sizes, int n_in,
                              void* d_out, int out_size, void* d_ws, size_t ws_size,
                              hipStream_t stream) {
  const float* x    = (const float*)d_in[0];
  const float* w    = (const float*)d_in[1];
  const float* bias = (const float*)d_in[2];
  float* out = (float*)d_out;
  u16* wbf2 = (u16*)d_ws;                                // 9.44 MB
  u16* xbf  = (u16*)((char*)d_ws + (16u << 20));         // 10.03 MB

  prep_kernel<<<dim3(5184), dim3(128), 0, stream>>>(w, x, wbf2, xbf);
  conv_mfma<<<dim3(256), dim3(256), 0, stream>>>(xbf, wbf2, bias, out);
}